// Round 5
// baseline (543.664 us; speedup 1.0000x reference)
//
#include <hip/hip_runtime.h>
#include <hip/hip_bf16.h>
#include <hip/hip_cooperative_groups.h>

namespace cg = cooperative_groups;

// B=4, S=512, T=32, D_MODEL=512, N_HEAD=8, D_HEAD=64;  BS=2048.
// Single cooperative kernel: converts+Tk | q-GEMM | qk-GEMM | attn | ao | out
// with grid.sync() between stages. Device functions are the R3-verified
// bodies (gemm64 = R1-verified XOR-swizzled staging; attn = R3 MFMA attn).
// Fallback: same device functions as 6 thin kernels if coop launch fails.

typedef __attribute__((ext_vector_type(8))) short frag8;   // 8 bf16
typedef __attribute__((ext_vector_type(4))) float f32x4;

__device__ __forceinline__ short f2s(float v) {
    return __builtin_bit_cast(short, __float2bfloat16(v));
}
__device__ __forceinline__ float s2f(short x) {
    return __builtin_bit_cast(float, (unsigned)(unsigned short)x << 16);
}
__device__ __forceinline__ void stv(float* p, float v)          { *p = v; }
__device__ __forceinline__ void stv(__hip_bfloat16* p, float v) { *p = __float2bfloat16(v); }

__device__ __forceinline__ void gl_lds16(const __hip_bfloat16* g, __hip_bfloat16* l) {
    __builtin_amdgcn_global_load_lds(
        (const __attribute__((address_space(1))) unsigned int*)g,
        (__attribute__((address_space(3))) unsigned int*)l, 16, 0, 0);
}

// ---------------- stage 1: converts (512 blocks x 1024 f4) + Tk (b<128) ----
__device__ __forceinline__
void stage_prep(int b, int tid, char* smem,
                const float* __restrict__ ipw, const float* __restrict__ opw,
                const float* __restrict__ src,
                __hip_bfloat16* __restrict__ ipw_bf, __hip_bfloat16* __restrict__ opw_bf,
                __hip_bfloat16* __restrict__ src_bf, __hip_bfloat16* __restrict__ Tk)
{
#pragma unroll
    for (int i = 0; i < 4; ++i) {
        int g = b * 1024 + i * 256 + tid;
        const float4* in; ushort4* o4; int off;
        if (g < 196608)      { in = (const float4*)ipw; o4 = (ushort4*)ipw_bf; off = g; }
        else if (g < 262144) { in = (const float4*)opw; o4 = (ushort4*)opw_bf; off = g - 196608; }
        else                 { in = (const float4*)src; o4 = (ushort4*)src_bf; off = g - 262144; }
        float4 v = in[off];
        ushort4 o;
        o.x = (unsigned short)f2s(v.x); o.y = (unsigned short)f2s(v.y);
        o.z = (unsigned short)f2s(v.z); o.w = (unsigned short)f2s(v.w);
        o4[off] = o;
    }
    if (b < 128) {   // 64x64 transpose tile: Tk[c,j] = bf16(ipw[512+j, c])
        short (*tile)[65] = (short(*)[65])smem;
        int bx = b & 15, by = b >> 4;
        const float* sp = ipw + (size_t)512 * 512;
#pragma unroll
        for (int i = 0; i < 16; ++i) {
            int idx = i * 256 + tid;
            int r = idx >> 6, c = idx & 63;
            tile[r][c] = f2s(sp[(size_t)(bx * 64 + r) * 512 + by * 64 + c]);
        }
        __syncthreads();
        short* Tks = (short*)Tk;
#pragma unroll
        for (int i = 0; i < 16; ++i) {
            int idx = i * 256 + tid;
            int rr = idx >> 6, cc = idx & 63;
            Tks[(size_t)(by * 64 + rr) * 1024 + bx * 64 + cc] = tile[cc][rr];
        }
        __syncthreads();
    }
}

// ---------------- 64x64-tile LDS-staged B^T GEMM (4 waves, XOR-swizzled) ----
// zmask != null: zero rows where all 32 mask ints are set (all tgt padded).
template<typename OUTT>
__device__ __forceinline__
void gemm64_dev(const __hip_bfloat16* __restrict__ A, const __hip_bfloat16* __restrict__ W,
                const float* __restrict__ bias, OUTT* __restrict__ C,
                const int* __restrict__ zmask,
                int N, int K, int tm, int tn, char* smem, int tid)
{
    short* sA = (short*)smem;          // 64*64
    short* sB = sA + 4096;
    int lane = tid & 63, w = tid >> 6;
    int wm = w >> 1, wn = w & 1;
    const __hip_bfloat16* Ab = A + (size_t)tm * 64 * K;
    const __hip_bfloat16* Wb = W + (size_t)tn * 64 * K;

    f32x4 acc[2][2];
#pragma unroll
    for (int i = 0; i < 2; ++i)
#pragma unroll
        for (int j = 0; j < 2; ++j) acc[i][j] = {0.f, 0.f, 0.f, 0.f};

    int wbase = (tid & ~63) * 8;
    int m = lane & 15, q = lane >> 4;
    int sw = (m & 7) * 8;                       // read-side XOR (shorts)
    int trow = tid >> 3;
    int tcb  = ((tid & 7) ^ (trow & 7)) * 8;    // pre-swizzled source col-block

    for (int k0 = 0; k0 < K; k0 += 64) {
        gl_lds16(Ab + (size_t)trow * K + k0 + tcb,        (__hip_bfloat16*)&sA[wbase]);
        gl_lds16(Ab + (size_t)(32 + trow) * K + k0 + tcb, (__hip_bfloat16*)&sA[2048 + wbase]);
        gl_lds16(Wb + (size_t)trow * K + k0 + tcb,        (__hip_bfloat16*)&sB[wbase]);
        gl_lds16(Wb + (size_t)(32 + trow) * K + k0 + tcb, (__hip_bfloat16*)&sB[2048 + wbase]);
        __syncthreads();
#pragma unroll
        for (int ki = 0; ki < 2; ++ki) {
            frag8 af[2], bf2[2];
#pragma unroll
            for (int i = 0; i < 2; ++i)
                af[i] = *(const frag8*)&sA[(wm * 32 + i * 16 + m) * 64 + ((ki * 32 + q * 8) ^ sw)];
#pragma unroll
            for (int j = 0; j < 2; ++j)
                bf2[j] = *(const frag8*)&sB[(wn * 32 + j * 16 + m) * 64 + ((ki * 32 + q * 8) ^ sw)];
#pragma unroll
            for (int i = 0; i < 2; ++i)
#pragma unroll
                for (int j = 0; j < 2; ++j)
                    acc[i][j] = __builtin_amdgcn_mfma_f32_16x16x32_bf16(
                        af[i], bf2[j], acc[i][j], 0, 0, 0);
        }
        __syncthreads();
    }

    int rb = q * 4;
    bool zr[2][4] = {{false,false,false,false},{false,false,false,false}};
    if (zmask) {
#pragma unroll
        for (int i = 0; i < 2; ++i)
#pragma unroll
            for (int t = 0; t < 4; ++t) {
                int row = tm * 64 + wm * 32 + i * 16 + rb + t;
                const uint4* mp = (const uint4*)(zmask + (size_t)row * 32);
                unsigned a = 0xffffffffu;
#pragma unroll
                for (int u = 0; u < 8; ++u) { uint4 v = mp[u]; a &= v.x & v.y & v.z & v.w; }
                zr[i][t] = (a != 0u);
            }
    }
#pragma unroll
    for (int j = 0; j < 2; ++j) {
        int   col = tn * 64 + wn * 32 + j * 16 + m;
        float bv  = bias[col];
#pragma unroll
        for (int i = 0; i < 2; ++i) {
            int row0 = tm * 64 + wm * 32 + i * 16 + rb;
#pragma unroll
            for (int t = 0; t < 4; ++t) {
                float v = acc[i][j][t] + bv;
                if (zr[i][t]) v = 0.f;
                stv(&C[(size_t)(row0 + t) * N + col], v);
            }
        }
    }
}

// ---------------- 32x32 wave-tile direct-global B^T GEMM --------------------
__device__ __forceinline__
void gemm_bt_wave(const __hip_bfloat16* __restrict__ A, int lda,
                  const __hip_bfloat16* __restrict__ W, int ldw,
                  const float* __restrict__ bias, int bc0,
                  __hip_bfloat16* __restrict__ C, int ldc,
                  int K, int tm, int tn, int lane)
{
    int r  = lane & 15;
    int kq = (lane >> 4) << 3;
    const __hip_bfloat16* Ap = A + (size_t)(tm * 32 + r) * lda + kq;
    const __hip_bfloat16* Wp = W + (size_t)(tn * 32 + r) * ldw + kq;

    f32x4 acc[2][2];
#pragma unroll
    for (int i = 0; i < 2; ++i)
#pragma unroll
        for (int j = 0; j < 2; ++j) acc[i][j] = {0.f, 0.f, 0.f, 0.f};

    for (int k0 = 0; k0 < K; k0 += 32) {
        frag8 a[2], b[2];
#pragma unroll
        for (int i = 0; i < 2; ++i) a[i] = *(const frag8*)(Ap + (size_t)i * 16 * lda + k0);
#pragma unroll
        for (int j = 0; j < 2; ++j) b[j] = *(const frag8*)(Wp + (size_t)j * 16 * ldw + k0);
#pragma unroll
        for (int i = 0; i < 2; ++i)
#pragma unroll
            for (int j = 0; j < 2; ++j)
                acc[i][j] = __builtin_amdgcn_mfma_f32_16x16x32_bf16(a[i], b[j], acc[i][j], 0, 0, 0);
    }

    int rb = (lane >> 4) * 4;
#pragma unroll
    for (int j = 0; j < 2; ++j) {
        int   col = tn * 32 + j * 16 + r;
        float bv  = bias ? bias[bc0 + col] : 0.f;
#pragma unroll
        for (int i = 0; i < 2; ++i) {
            int row0 = tm * 32 + i * 16 + rb;
#pragma unroll
            for (int t = 0; t < 4; ++t)
                C[(size_t)(row0 + t) * ldc + col] = __float2bfloat16(acc[i][j][t] + bv);
        }
    }
}

// ---------------- attn: score + softmax + tbar for one (b,s) ----------------
// R3-verified body. smem layout (shorts): sS[16640] | sTT[16384] | sQK[4160] | sM
__device__ __forceinline__
void attn_dev(int bs, char* smem, const float* __restrict__ tgt,
              const __hip_bfloat16* __restrict__ qkh, const int* __restrict__ mask,
              __hip_bfloat16* __restrict__ tbar, int tid)
{
    int lane = tid & 63, wv = tid >> 6, m = lane & 15, g4 = lane >> 4;
    short* sS  = (short*)smem;
    short* sTT = sS + 16640;
    short* sQK = sTT + 16384;
    int*   sM  = (int*)(sQK + 4160);

    const float* tg = tgt + (size_t)bs * 32 * 512;
#pragma unroll
    for (int i = 0; i < 16; ++i) {
        int idx = i * 256 + tid;
        int row = idx >> 7, c4 = (idx & 127) * 4;
        float4 v = *(const float4*)(tg + (size_t)row * 512 + c4);
        ushort4 o;
        o.x = (unsigned short)f2s(v.x); o.y = (unsigned short)f2s(v.y);
        o.z = (unsigned short)f2s(v.z); o.w = (unsigned short)f2s(v.w);
        *(ushort4*)&sS[row * 520 + c4] = o;
    }
    const ushort4* qk4 = (const ushort4*)(qkh + (size_t)bs * 4096);
#pragma unroll
    for (int i = 0; i < 4; ++i) {
        int u = i * 256 + tid;
        int h = u >> 7, c4 = (u & 127) * 4;
        *(ushort4*)&sQK[h * 520 + c4] = qk4[u];
    }
    if (tid < 32) sM[tid] = mask[bs * 32 + tid];
    __syncthreads();

    {   // transpose sTT[c][t] = sS[t][c], lane-staggered
        int rot = (tid >> 1) & 7;
#pragma unroll
        for (int cc = 0; cc < 2; ++cc) {
            int c = tid + cc * 256;
#pragma unroll
            for (int s = 0; s < 8; ++s) {
                int t0 = ((s + rot) & 7) * 4;
                ushort4 o;
                o.x = (unsigned short)sS[(t0 + 0) * 520 + c];
                o.y = (unsigned short)sS[(t0 + 1) * 520 + c];
                o.z = (unsigned short)sS[(t0 + 2) * 520 + c];
                o.w = (unsigned short)sS[(t0 + 3) * 520 + c];
                *(ushort4*)&sTT[c * 32 + t0] = o;
            }
        }
    }
    int mk0 = sM[m], mk1 = sM[16 + m];
    bool allm = __all((mk0 != 0) && (mk1 != 0));

    f32x4 acc0 = {0.f,0.f,0.f,0.f}, acc1 = {0.f,0.f,0.f,0.f};
    {
        const short* qb  = &sQK[(m & 7) * 520 + g4 * 8];
        const short* t0p = &sS[m * 520 + g4 * 8];
        const short* t1p = t0p + 16 * 520;
#pragma unroll
        for (int k0 = 0; k0 < 512; k0 += 32) {
            frag8 af = *(const frag8*)(qb + k0);
            frag8 b0 = *(const frag8*)(t0p + k0);
            frag8 b1 = *(const frag8*)(t1p + k0);
            acc0 = __builtin_amdgcn_mfma_f32_16x16x32_bf16(af, b0, acc0, 0, 0, 0);
            acc1 = __builtin_amdgcn_mfma_f32_16x16x32_bf16(af, b1, acc1, 0, 0, 0);
        }
    }
    float p0v[4], p1v[4];
#pragma unroll
    for (int r = 0; r < 4; ++r) {
        float s0 = acc0[r] * 0.125f, s1 = acc1[r] * 0.125f;
        if (!allm) {
            if (mk0) s0 = -__builtin_inff();
            if (mk1) s1 = -__builtin_inff();
        }
        float mx = fmaxf(s0, s1);
#pragma unroll
        for (int off = 1; off < 16; off <<= 1) mx = fmaxf(mx, __shfl_xor(mx, off));
        float e0 = __expf(s0 - mx), e1 = __expf(s1 - mx);
        float sm = e0 + e1;
#pragma unroll
        for (int off = 1; off < 16; off <<= 1) sm += __shfl_xor(sm, off);
        float inv = 1.f / sm;
        p0v[r] = e0 * inv; p1v[r] = e1 * inv;
    }
    __syncthreads();                    // sQK score-reads done -> sP overlay
    short* sPw = sQK + wv * 512;
    if (g4 < 2) {
#pragma unroll
        for (int r = 0; r < 4; ++r) {
            int h = g4 * 4 + r;
            short h0 = f2s(p0v[r]), h1 = f2s(p1v[r]);
            sPw[h * 32 + m]            = h0;
            sPw[h * 32 + 16 + m]       = h1;
            sPw[256 + h * 32 + m]      = f2s(p0v[r] - s2f(h0));
            sPw[256 + h * 32 + 16 + m] = f2s(p1v[r] - s2f(h1));
        }
    }
    __syncthreads();
    frag8 paH = *(const frag8*)(sPw + (m & 7) * 32 + g4 * 8);
    frag8 paL = *(const frag8*)(sPw + 256 + (m & 7) * 32 + g4 * 8);

    short* sO = sS;                     // sS dead -> output staging
#pragma unroll
    for (int ci = 0; ci < 8; ++ci) {
        int cg = wv * 8 + ci;
        frag8 vb = *(const frag8*)(&sTT[(cg * 16 + m) * 32 + g4 * 8]);
        f32x4 d = {0.f,0.f,0.f,0.f};
        d = __builtin_amdgcn_mfma_f32_16x16x32_bf16(paH, vb, d, 0, 0, 0);
        d = __builtin_amdgcn_mfma_f32_16x16x32_bf16(paL, vb, d, 0, 0, 0);
        if (g4 < 2) {
#pragma unroll
            for (int r = 0; r < 4; ++r)
                sO[(g4 * 4 + r) * 512 + cg * 16 + m] = f2s(d[r]);
        }
    }
    __syncthreads();
    ushort4* dst = (ushort4*)(tbar + (size_t)bs * 4096);
    const ushort4* so4 = (const ushort4*)sO;
#pragma unroll
    for (int i = 0; i < 4; ++i)
        dst[i * 256 + tid] = so4[i * 256 + tid];
}

// ---------------- the single cooperative kernel -----------------------------
__global__ __launch_bounds__(256, 2)
void fused_all(const float* src, const float* tgt, const int* mask,
               const float* ipw, const float* ipb,
               const float* opw, const float* opb, float* out,
               __hip_bfloat16* src_bf, __hip_bfloat16* ipw_bf,
               __hip_bfloat16* opw_bf, __hip_bfloat16* q_bf,
               __hip_bfloat16* Tk, __hip_bfloat16* qkh,
               __hip_bfloat16* tbar, __hip_bfloat16* ao_bf)
{
    cg::grid_group gg = cg::this_grid();
    __shared__ __align__(16) char smem[74496];
    int b = blockIdx.x, tid = threadIdx.x;
    int lane = tid & 63, wv = tid >> 6;

    // 1) converts + Tk transpose
    stage_prep(b, tid, smem, ipw, opw, src, ipw_bf, opw_bf, src_bf, Tk);
    gg.sync();

    // 2) q = src @ Wq^T + b_q   (64x64 tiles, 256 active blocks)
    if (b < 256)
        gemm64_dev<__hip_bfloat16>(src_bf, ipw_bf, ipb, q_bf, nullptr,
                                   512, 512, b >> 3, b & 7, smem, tid);
    gg.sync();

    // 3) qk[m, h*512+c] = sum_d q[m,h*64+d] * Tk[c, h*64+d]   (8192 wave-tiles)
#pragma unroll
    for (int rep = 0; rep < 4; ++rep) {
        int t = b * 4 + wv + rep * 2048;
        int z = t >> 10, loc = t & 1023;
        gemm_bt_wave(q_bf + z * 64, 512, Tk + z * 64, 1024, nullptr, 0,
                     qkh + (size_t)z * 512, 4096, 64, loc >> 4, loc & 15, lane);
    }
    gg.sync();

    // 4) attn: 4 sequential (b,s) per block
    for (int rep = 0; rep < 4; ++rep) {
        attn_dev(b + rep * 512, smem, tgt, qkh, mask, tbar, tid);
        __syncthreads();
    }
    gg.sync();

    // 5) ao[m, h*64+n] = sum_c tbar[m,h,c]*Wv[h*64+n,c] + b_v  (1024 wave-tiles)
    {
        int gw = b * 4 + wv;
        if (gw < 1024) {
            int z = gw >> 7, loc = gw & 127;
            gemm_bt_wave(tbar + (size_t)z * 512, 4096,
                         ipw_bf + (size_t)(1024 + z * 64) * 512, 512,
                         ipb + 1024, z * 64,
                         ao_bf + z * 64, 512, 512, loc >> 1, loc & 1, lane);
        }
    }
    gg.sync();

    // 6) out = ao @ Wout^T + b_out, zero all-masked rows
    if (b < 256)
        gemm64_dev<float>(ao_bf, opw_bf, opb, out, mask,
                          512, 512, b >> 3, b & 7, smem, tid);
}

// ---------------- fallback thin kernels (same device bodies) ----------------
__global__ __launch_bounds__(256)
void k_prep(const float* ipw, const float* opw, const float* src,
            __hip_bfloat16* ipw_bf, __hip_bfloat16* opw_bf,
            __hip_bfloat16* src_bf, __hip_bfloat16* Tk)
{
    __shared__ __align__(16) char smem[8320];
    stage_prep(blockIdx.x, threadIdx.x, smem, ipw, opw, src, ipw_bf, opw_bf, src_bf, Tk);
}
__global__ __launch_bounds__(256)
void k_q(const __hip_bfloat16* src_bf, const __hip_bfloat16* ipw_bf,
         const float* ipb, __hip_bfloat16* q_bf)
{
    __shared__ __align__(16) char smem[16384];
    int b = blockIdx.x;
    gemm64_dev<__hip_bfloat16>(src_bf, ipw_bf, ipb, q_bf, nullptr,
                               512, 512, b >> 3, b & 7, smem, threadIdx.x);
}
__global__ __launch_bounds__(256)
void k_qk(const __hip_bfloat16* q_bf, const __hip_bfloat16* Tk, __hip_bfloat16* qkh)
{
    int tid = threadIdx.x;
    int t = blockIdx.x * 4 + (tid >> 6);
    int z = t >> 10, loc = t & 1023;
    gemm_bt_wave(q_bf + z * 64, 512, Tk + z * 64, 1024, nullptr, 0,
                 qkh + (size_t)z * 512, 4096, 64, loc >> 4, loc & 15, tid & 63);
}
__global__ __launch_bounds__(256)
void k_attn(const float* tgt, const __hip_bfloat16* qkh, const int* mask,
            __hip_bfloat16* tbar)
{
    __shared__ __align__(16) char smem[74496];
    attn_dev(blockIdx.x, smem, tgt, qkh, mask, tbar, threadIdx.x);
}
__global__ __launch_bounds__(256)
void k_ao(const __hip_bfloat16* tbar, const __hip_bfloat16* ipw_bf,
          const float* ipb, __hip_bfloat16* ao_bf)
{
    int tid = threadIdx.x;
    int gw = blockIdx.x * 4 + (tid >> 6);
    int z = gw >> 7, loc = gw & 127;
    gemm_bt_wave(tbar + (size_t)z * 512, 4096,
                 ipw_bf + (size_t)(1024 + z * 64) * 512, 512,
                 ipb + 1024, z * 64, ao_bf + z * 64, 512, 512,
                 loc >> 1, loc & 1, tid & 63);
}
__global__ __launch_bounds__(256)
void k_out(const __hip_bfloat16* ao_bf, const __hip_bfloat16* opw_bf,
           const float* opb, float* out, const int* mask)
{
    __shared__ __align__(16) char smem[16384];
    int b = blockIdx.x;
    gemm64_dev<float>(ao_bf, opw_bf, opb, out, mask,
                      512, 512, b >> 3, b & 7, smem, threadIdx.x);
}

extern "C" void kernel_launch(void* const* d_in, const int* in_sizes, int n_in,
                              void* d_out, int out_size, void* d_ws, size_t ws_size,
                              hipStream_t stream)
{
    const float* src  = (const float*)d_in[0]; // (2048,512)
    const float* tgt  = (const float*)d_in[1]; // (65536,512)
    const int*   mask = (const int*)d_in[2];   // (2048,32)
    const float* ipw  = (const float*)d_in[3]; // (1536,512)
    const float* ipb  = (const float*)d_in[4]; // (1536,)
    const float* opw  = (const float*)d_in[5]; // (512,512)
    const float* opb  = (const float*)d_in[6]; // (512,)
    float*       out  = (float*)d_out;         // (2048,512)

    char* ws = (char*)d_ws;
    __hip_bfloat16* src_bf = (__hip_bfloat16*)(ws);
    __hip_bfloat16* ipw_bf = (__hip_bfloat16*)(ws + ((size_t)2 << 20));
    __hip_bfloat16* opw_bf = (__hip_bfloat16*)(ws + ((size_t)2 << 20) + 1536 * 512 * 2);
    __hip_bfloat16* q_bf   = (__hip_bfloat16*)(ws + ((size_t)4 << 20));
    __hip_bfloat16* Tk     = (__hip_bfloat16*)(ws + ((size_t)6 << 20));
    __hip_bfloat16* qkh    = (__hip_bfloat16*)(ws + ((size_t)8 << 20));
    __hip_bfloat16* tbar   = (__hip_bfloat16*)(ws + ((size_t)24 << 20));
    __hip_bfloat16* ao_bf  = (__hip_bfloat16*)(ws + ((size_t)40 << 20));

    void* args[16] = {
        (void*)&src, (void*)&tgt, (void*)&mask, (void*)&ipw, (void*)&ipb,
        (void*)&opw, (void*)&opb, (void*)&out,
        (void*)&src_bf, (void*)&ipw_bf, (void*)&opw_bf, (void*)&q_bf,
        (void*)&Tk, (void*)&qkh, (void*)&tbar, (void*)&ao_bf
    };
    hipError_t e = hipLaunchCooperativeKernel((const void*)fused_all,
                                              dim3(512), dim3(256),
                                              (void**)args, 0, stream);
    if (e != hipSuccess) {
        // fallback: 6 serial launches of the same stage bodies
        k_prep<<<512, 256, 0, stream>>>(ipw, opw, src, ipw_bf, opw_bf, src_bf, Tk);
        k_q   <<<256, 256, 0, stream>>>(src_bf, ipw_bf, ipb, q_bf);
        k_qk  <<<2048, 256, 0, stream>>>(q_bf, Tk, qkh);
        k_attn<<<2048, 256, 0, stream>>>(tgt, qkh, mask, tbar);
        k_ao  <<<256, 256, 0, stream>>>(tbar, ipw_bf, ipb, ao_bf);
        k_out <<<256, 256, 0, stream>>>(ao_bf, opw_bf, opb, out, mask);
    }
}

// Round 6
// 252.655 us; speedup vs baseline: 2.1518x; 2.1518x over previous
//
#include <hip/hip_runtime.h>
#include <hip/hip_bf16.h>

// B=4, S=512, T=32, D_MODEL=512, N_HEAD=8, D_HEAD=64;  BS=2048.
// R6: revert cooperative fusion (grid.sync spin ~275us, occupancy-capped) back
// to 6 thin launches of the HW-verified device bodies (R5 run passed).
// k_attn improved: sTT transpose pass deleted (each element was written once,
// read once -> zero reuse). PV B-frags read as 8x ds_read_u16 columns of sS;
// output staging overlays dead sP/sQK. LDS 74.5 -> 41.7 KB = 3 blocks/CU.
//
// Decomposition established in R5: harness fixed cost ~157us (2x536MB poison
// fills); our pipeline ~110us; tgt fp32 read (134MB ~ 21us) is the floor.

typedef __attribute__((ext_vector_type(8))) short frag8;   // 8 bf16
typedef __attribute__((ext_vector_type(4))) float f32x4;

__device__ __forceinline__ short f2s(float v) {
    return __builtin_bit_cast(short, __float2bfloat16(v));
}
__device__ __forceinline__ float s2f(short x) {
    return __builtin_bit_cast(float, (unsigned)(unsigned short)x << 16);
}
__device__ __forceinline__ void stv(float* p, float v)          { *p = v; }
__device__ __forceinline__ void stv(__hip_bfloat16* p, float v) { *p = __float2bfloat16(v); }

__device__ __forceinline__ void gl_lds16(const __hip_bfloat16* g, __hip_bfloat16* l) {
    __builtin_amdgcn_global_load_lds(
        (const __attribute__((address_space(1))) unsigned int*)g,
        (__attribute__((address_space(3))) unsigned int*)l, 16, 0, 0);
}

// ---------------- prep: converts (512 blocks x 1024 f4) + Tk (b<128) --------
__global__ __launch_bounds__(256)
void k_prep(const float* __restrict__ ipw, const float* __restrict__ opw,
            const float* __restrict__ src,
            __hip_bfloat16* __restrict__ ipw_bf, __hip_bfloat16* __restrict__ opw_bf,
            __hip_bfloat16* __restrict__ src_bf, __hip_bfloat16* __restrict__ Tk)
{
    __shared__ short tile[64][65];
    int b = blockIdx.x, tid = threadIdx.x;
#pragma unroll
    for (int i = 0; i < 4; ++i) {
        int g = b * 1024 + i * 256 + tid;
        const float4* in; ushort4* o4; int off;
        if (g < 196608)      { in = (const float4*)ipw; o4 = (ushort4*)ipw_bf; off = g; }
        else if (g < 262144) { in = (const float4*)opw; o4 = (ushort4*)opw_bf; off = g - 196608; }
        else                 { in = (const float4*)src; o4 = (ushort4*)src_bf; off = g - 262144; }
        float4 v = in[off];
        ushort4 o;
        o.x = (unsigned short)f2s(v.x); o.y = (unsigned short)f2s(v.y);
        o.z = (unsigned short)f2s(v.z); o.w = (unsigned short)f2s(v.w);
        o4[off] = o;
    }
    if (b < 128) {   // 64x64 transpose tile: Tk[c,j] = bf16(ipw[512+j, c])
        int bx = b & 15, by = b >> 4;
        const float* sp = ipw + (size_t)512 * 512;
#pragma unroll
        for (int i = 0; i < 16; ++i) {
            int idx = i * 256 + tid;
            int r = idx >> 6, c = idx & 63;
            tile[r][c] = f2s(sp[(size_t)(bx * 64 + r) * 512 + by * 64 + c]);
        }
        __syncthreads();
        short* Tks = (short*)Tk;
#pragma unroll
        for (int i = 0; i < 16; ++i) {
            int idx = i * 256 + tid;
            int rr = idx >> 6, cc = idx & 63;
            Tks[(size_t)(by * 64 + rr) * 1024 + bx * 64 + cc] = tile[cc][rr];
        }
    }
}

// ---------------- 64x64-tile LDS-staged B^T GEMM (4 waves, XOR-swizzled) ----
template<typename OUTT>
__device__ __forceinline__
void gemm64_dev(const __hip_bfloat16* __restrict__ A, const __hip_bfloat16* __restrict__ W,
                const float* __restrict__ bias, OUTT* __restrict__ C,
                const int* __restrict__ zmask,
                int N, int K, int tm, int tn, char* smem, int tid)
{
    short* sA = (short*)smem;          // 64*64
    short* sB = sA + 4096;
    int lane = tid & 63, w = tid >> 6;
    int wm = w >> 1, wn = w & 1;
    const __hip_bfloat16* Ab = A + (size_t)tm * 64 * K;
    const __hip_bfloat16* Wb = W + (size_t)tn * 64 * K;

    f32x4 acc[2][2];
#pragma unroll
    for (int i = 0; i < 2; ++i)
#pragma unroll
        for (int j = 0; j < 2; ++j) acc[i][j] = {0.f, 0.f, 0.f, 0.f};

    int wbase = (tid & ~63) * 8;
    int m = lane & 15, q = lane >> 4;
    int sw = (m & 7) * 8;                       // read-side XOR (shorts)
    int trow = tid >> 3;
    int tcb  = ((tid & 7) ^ (trow & 7)) * 8;    // pre-swizzled source col-block

    for (int k0 = 0; k0 < K; k0 += 64) {
        gl_lds16(Ab + (size_t)trow * K + k0 + tcb,        (__hip_bfloat16*)&sA[wbase]);
        gl_lds16(Ab + (size_t)(32 + trow) * K + k0 + tcb, (__hip_bfloat16*)&sA[2048 + wbase]);
        gl_lds16(Wb + (size_t)trow * K + k0 + tcb,        (__hip_bfloat16*)&sB[wbase]);
        gl_lds16(Wb + (size_t)(32 + trow) * K + k0 + tcb, (__hip_bfloat16*)&sB[2048 + wbase]);
        __syncthreads();
#pragma unroll
        for (int ki = 0; ki < 2; ++ki) {
            frag8 af[2], bf2[2];
#pragma unroll
            for (int i = 0; i < 2; ++i)
                af[i] = *(const frag8*)&sA[(wm * 32 + i * 16 + m) * 64 + ((ki * 32 + q * 8) ^ sw)];
#pragma unroll
            for (int j = 0; j < 2; ++j)
                bf2[j] = *(const frag8*)&sB[(wn * 32 + j * 16 + m) * 64 + ((ki * 32 + q * 8) ^ sw)];
#pragma unroll
            for (int i = 0; i < 2; ++i)
#pragma unroll
                for (int j = 0; j < 2; ++j)
                    acc[i][j] = __builtin_amdgcn_mfma_f32_16x16x32_bf16(
                        af[i], bf2[j], acc[i][j], 0, 0, 0);
        }
        __syncthreads();
    }

    int rb = q * 4;
    bool zr[2][4] = {{false,false,false,false},{false,false,false,false}};
    if (zmask) {
#pragma unroll
        for (int i = 0; i < 2; ++i)
#pragma unroll
            for (int t = 0; t < 4; ++t) {
                int row = tm * 64 + wm * 32 + i * 16 + rb + t;
                const uint4* mp = (const uint4*)(zmask + (size_t)row * 32);
                unsigned a = 0xffffffffu;
#pragma unroll
                for (int u = 0; u < 8; ++u) { uint4 v = mp[u]; a &= v.x & v.y & v.z & v.w; }
                zr[i][t] = (a != 0u);
            }
    }
#pragma unroll
    for (int j = 0; j < 2; ++j) {
        int   col = tn * 64 + wn * 32 + j * 16 + m;
        float bv  = bias[col];
#pragma unroll
        for (int i = 0; i < 2; ++i) {
            int row0 = tm * 64 + wm * 32 + i * 16 + rb;
#pragma unroll
            for (int t = 0; t < 4; ++t) {
                float v = acc[i][j][t] + bv;
                if (zr[i][t]) v = 0.f;
                stv(&C[(size_t)(row0 + t) * N + col], v);
            }
        }
    }
}

// ---------------- 32x32 wave-tile direct-global B^T GEMM --------------------
__device__ __forceinline__
void gemm_bt_wave(const __hip_bfloat16* __restrict__ A, int lda,
                  const __hip_bfloat16* __restrict__ W, int ldw,
                  const float* __restrict__ bias, int bc0,
                  __hip_bfloat16* __restrict__ C, int ldc,
                  int K, int tm, int tn, int lane)
{
    int r  = lane & 15;
    int kq = (lane >> 4) << 3;
    const __hip_bfloat16* Ap = A + (size_t)(tm * 32 + r) * lda + kq;
    const __hip_bfloat16* Wp = W + (size_t)(tn * 32 + r) * ldw + kq;

    f32x4 acc[2][2];
#pragma unroll
    for (int i = 0; i < 2; ++i)
#pragma unroll
        for (int j = 0; j < 2; ++j) acc[i][j] = {0.f, 0.f, 0.f, 0.f};

    for (int k0 = 0; k0 < K; k0 += 32) {
        frag8 a[2], b[2];
#pragma unroll
        for (int i = 0; i < 2; ++i) a[i] = *(const frag8*)(Ap + (size_t)i * 16 * lda + k0);
#pragma unroll
        for (int j = 0; j < 2; ++j) b[j] = *(const frag8*)(Wp + (size_t)j * 16 * ldw + k0);
#pragma unroll
        for (int i = 0; i < 2; ++i)
#pragma unroll
            for (int j = 0; j < 2; ++j)
                acc[i][j] = __builtin_amdgcn_mfma_f32_16x16x32_bf16(a[i], b[j], acc[i][j], 0, 0, 0);
    }

    int rb = (lane >> 4) * 4;
#pragma unroll
    for (int j = 0; j < 2; ++j) {
        int   col = tn * 32 + j * 16 + r;
        float bv  = bias ? bias[bc0 + col] : 0.f;
#pragma unroll
        for (int i = 0; i < 2; ++i) {
            int row0 = tm * 32 + i * 16 + rb;
#pragma unroll
            for (int t = 0; t < 4; ++t)
                C[(size_t)(row0 + t) * ldc + col] = __float2bfloat16(acc[i][j][t] + bv);
        }
    }
}

__global__ __launch_bounds__(256)
void k_q(const __hip_bfloat16* src_bf, const __hip_bfloat16* ipw_bf,
         const float* ipb, __hip_bfloat16* q_bf)
{
    __shared__ __align__(16) char smem[16384];
    int b = blockIdx.x;
    gemm64_dev<__hip_bfloat16>(src_bf, ipw_bf, ipb, q_bf, nullptr,
                               512, 512, b >> 3, b & 7, smem, threadIdx.x);
}

__global__ __launch_bounds__(256)
void k_qk(const __hip_bfloat16* q_bf, const __hip_bfloat16* Tk, __hip_bfloat16* qkh)
{
    int tid = threadIdx.x;
    int t = blockIdx.x * 4 + (tid >> 6);
    int z = t >> 10, loc = t & 1023;
    gemm_bt_wave(q_bf + z * 64, 512, Tk + z * 64, 1024, nullptr, 0,
                 qkh + (size_t)z * 512, 4096, 64, loc >> 4, loc & 15, tid & 63);
}

// ---------------- attn: score + softmax + tbar, transposeless PV ------------
// One 256-thr block per (b,s). LDS 41.7KB -> 3 blocks/CU.
// score: S[h][t] = qk x T (proven D=X.Y^T frag convention, rows of sQK / sS).
// PV: tbar[h][c] = P x T; B-frag element j = T[g4*8+j, cg*16+m] read directly
//     as ds_read_u16 columns of sS (the old sTT had zero reuse: each element
//     written once, read once -> direct reads are strictly fewer LDS ops).
// sP overlays sQK after score; sO overlays sP after paH/paL are in registers.
__global__ __launch_bounds__(256)
void k_attn(const float* __restrict__ tgt,
            const __hip_bfloat16* __restrict__ qkh,
            const int* __restrict__ mask,
            __hip_bfloat16* __restrict__ tbar)
{
    int bs   = blockIdx.x;
    int tid  = threadIdx.x;
    int lane = tid & 63;
    int wv   = tid >> 6;
    int m    = lane & 15;
    int g4   = lane >> 4;

    __shared__ short sS[32 * 520];    // 33,280 B  (T row-major, bf16)
    __shared__ short sQK[8 * 520];    // 8,320 B   (qk rows; later sP, then sO)
    __shared__ int   sM[32];

    // ---- stage tgt fp32 -> bf16, row-major ----
    const float* tg = tgt + (size_t)bs * 32 * 512;
#pragma unroll
    for (int i = 0; i < 16; ++i) {
        int idx = i * 256 + tid;
        int row = idx >> 7, c4 = (idx & 127) * 4;
        float4 v = *(const float4*)(tg + (size_t)row * 512 + c4);
        ushort4 o;
        o.x = (unsigned short)f2s(v.x); o.y = (unsigned short)f2s(v.y);
        o.z = (unsigned short)f2s(v.z); o.w = (unsigned short)f2s(v.w);
        *(ushort4*)&sS[row * 520 + c4] = o;
    }
    const ushort4* qk4 = (const ushort4*)(qkh + (size_t)bs * 4096);
#pragma unroll
    for (int i = 0; i < 4; ++i) {
        int u = i * 256 + tid;
        int h = u >> 7, c4 = (u & 127) * 4;
        *(ushort4*)&sQK[h * 520 + c4] = qk4[u];
    }
    if (tid < 32) sM[tid] = mask[bs * 32 + tid];
    __syncthreads();

    int mk0 = sM[m], mk1 = sM[16 + m];
    bool allm = __all((mk0 != 0) && (mk1 != 0));

    // ---- score: every wave computes full 16x32 S redundantly ----
    f32x4 acc0 = {0.f,0.f,0.f,0.f}, acc1 = {0.f,0.f,0.f,0.f};
    {
        const short* qb  = &sQK[(m & 7) * 520 + g4 * 8];
        const short* t0p = &sS[m * 520 + g4 * 8];
        const short* t1p = t0p + 16 * 520;
#pragma unroll
        for (int k0 = 0; k0 < 512; k0 += 32) {
            frag8 af = *(const frag8*)(qb + k0);
            frag8 b0 = *(const frag8*)(t0p + k0);
            frag8 b1 = *(const frag8*)(t1p + k0);
            acc0 = __builtin_amdgcn_mfma_f32_16x16x32_bf16(af, b0, acc0, 0, 0, 0);
            acc1 = __builtin_amdgcn_mfma_f32_16x16x32_bf16(af, b1, acc1, 0, 0, 0);
        }
    }

    // ---- softmax over t per row h = g4*4+r (16-lane shfl reduce) ----
    float p0v[4], p1v[4];
#pragma unroll
    for (int r = 0; r < 4; ++r) {
        float s0 = acc0[r] * 0.125f, s1 = acc1[r] * 0.125f;
        if (!allm) {
            if (mk0) s0 = -__builtin_inff();
            if (mk1) s1 = -__builtin_inff();
        }
        float mx = fmaxf(s0, s1);
#pragma unroll
        for (int off = 1; off < 16; off <<= 1) mx = fmaxf(mx, __shfl_xor(mx, off));
        float e0 = __expf(s0 - mx), e1 = __expf(s1 - mx);
        float sm = e0 + e1;
#pragma unroll
        for (int off = 1; off < 16; off <<= 1) sm += __shfl_xor(sm, off);
        float inv = 1.f / sm;
        p0v[r] = e0 * inv; p1v[r] = e1 * inv;
    }
    __syncthreads();                    // score reads of sQK done -> sP overlay

    short* sPw = sQK + wv * 512;        // per-wave: 256 hi + 256 lo
    if (g4 < 2) {
#pragma unroll
        for (int r = 0; r < 4; ++r) {
            int h = g4 * 4 + r;
            short h0 = f2s(p0v[r]), h1 = f2s(p1v[r]);
            sPw[h * 32 + m]            = h0;
            sPw[h * 32 + 16 + m]       = h1;
            sPw[256 + h * 32 + m]      = f2s(p0v[r] - s2f(h0));
            sPw[256 + h * 32 + 16 + m] = f2s(p1v[r] - s2f(h1));
        }
    }
    __syncthreads();
    frag8 paH = *(const frag8*)(sPw + (m & 7) * 32 + g4 * 8);
    frag8 paL = *(const frag8*)(sPw + 256 + (m & 7) * 32 + g4 * 8);
    __syncthreads();                    // sP in registers -> sO overlay of sQK

    // ---- PV: B-frag = direct column reads of sS; out to sO staging ----
    short* sO = sQK;                    // 8x512 = 4096 shorts (fits 4160)
#pragma unroll
    for (int ci = 0; ci < 8; ++ci) {
        int cg = wv * 8 + ci;
        int cbase = cg * 16 + m;
        frag8 vb;
#pragma unroll
        for (int j = 0; j < 8; ++j)
            vb[j] = sS[(g4 * 8 + j) * 520 + cbase];
        f32x4 d = {0.f,0.f,0.f,0.f};
        d = __builtin_amdgcn_mfma_f32_16x16x32_bf16(paH, vb, d, 0, 0, 0);
        d = __builtin_amdgcn_mfma_f32_16x16x32_bf16(paL, vb, d, 0, 0, 0);
        if (g4 < 2) {
#pragma unroll
            for (int r = 0; r < 4; ++r)
                sO[(g4 * 4 + r) * 512 + cg * 16 + m] = f2s(d[r]);
        }
    }
    __syncthreads();

    // ---- coalesced copy-out (8x512 bf16 = 1024 ushort4) ----
    ushort4* dst = (ushort4*)(tbar + (size_t)bs * 4096);
    const ushort4* so4 = (const ushort4*)sO;
#pragma unroll
    for (int i = 0; i < 4; ++i)
        dst[i * 256 + tid] = so4[i * 256 + tid];
}

__global__ __launch_bounds__(256)
void k_ao(const __hip_bfloat16* tbar, const __hip_bfloat16* ipw_bf,
          const float* ipb, __hip_bfloat16* ao_bf)
{
    int tid = threadIdx.x;
    int gw = blockIdx.x * 4 + (tid >> 6);
    int z = gw >> 7, loc = gw & 127;
    gemm_bt_wave(tbar + (size_t)z * 512, 4096,
                 ipw_bf + (size_t)(1024 + z * 64) * 512, 512,
                 ipb + 1024, z * 64, ao_bf + z * 64, 512, 512,
                 loc >> 1, loc & 1, tid & 63);
}

__global__ __launch_bounds__(256)
void k_out(const __hip_bfloat16* ao_bf, const __hip_bfloat16* opw_bf,
           const float* opb, float* out, const int* mask)
{
    __shared__ __align__(16) char smem[16384];
    int b = blockIdx.x;
    gemm64_dev<float>(ao_bf, opw_bf, opb, out, mask,
                      512, 512, b >> 3, b & 7, smem, threadIdx.x);
}

extern "C" void kernel_launch(void* const* d_in, const int* in_sizes, int n_in,
                              void* d_out, int out_size, void* d_ws, size_t ws_size,
                              hipStream_t stream)
{
    const float* src  = (const float*)d_in[0]; // (2048,512)
    const float* tgt  = (const float*)d_in[1]; // (65536,512)
    const int*   mask = (const int*)d_in[2];   // (2048,32)
    const float* ipw  = (const float*)d_in[3]; // (1536,512)
    const float* ipb  = (const float*)d_in[4]; // (1536,)
    const float* opw  = (const float*)d_in[5]; // (512,512)
    const float* opb  = (const float*)d_in[6]; // (512,)
    float*       out  = (float*)d_out;         // (2048,512)

    char* ws = (char*)d_ws;
    __hip_bfloat16* src_bf = (__hip_bfloat16*)(ws);
    __hip_bfloat16* ipw_bf = (__hip_bfloat16*)(ws + ((size_t)2 << 20));
    __hip_bfloat16* opw_bf = (__hip_bfloat16*)(ws + ((size_t)2 << 20) + 1536 * 512 * 2);
    __hip_bfloat16* q_bf   = (__hip_bfloat16*)(ws + ((size_t)4 << 20));
    __hip_bfloat16* Tk     = (__hip_bfloat16*)(ws + ((size_t)6 << 20));
    __hip_bfloat16* qkh    = (__hip_bfloat16*)(ws + ((size_t)8 << 20));
    __hip_bfloat16* tbar   = (__hip_bfloat16*)(ws + ((size_t)24 << 20));
    __hip_bfloat16* ao_bf  = (__hip_bfloat16*)(ws + ((size_t)40 << 20));

    k_prep<<<512, 256, 0, stream>>>(ipw, opw, src, ipw_bf, opw_bf, src_bf, Tk);
    k_q   <<<256, 256, 0, stream>>>(src_bf, ipw_bf, ipb, q_bf);
    k_qk  <<<2048, 256, 0, stream>>>(q_bf, Tk, qkh);
    k_attn<<<2048, 256, 0, stream>>>(tgt, qkh, mask, tbar);
    k_ao  <<<256, 256, 0, stream>>>(tbar, ipw_bf, ipb, ao_bf);
    k_out <<<256, 256, 0, stream>>>(ao_bf, opw_bf, opb, out, mask);
}